// Round 9
// baseline (477.469 us; speedup 1.0000x reference)
//
#include <hip/hip_runtime.h>
#include <cmath>

namespace {
constexpr int BPTS  = 16384;
constexpr int NPOSE = 32;
constexpr int KV    = 8;
constexpr int HD    = 256;
constexpr int TM    = 128;      // points per block (mlp)
constexpr float TAU = 0.03f;    // argmin ambiguity threshold

constexpr size_t OFF_XLOCAL = 0;
constexpr size_t OFF_XLA    = (size_t)BPTS * 3;
constexpr size_t OFF_MINENC = OFF_XLA + (size_t)NPOSE * BPTS * 3;
constexpr size_t OFF_POSEQ  = OFF_MINENC + (size_t)BPTS * NPOSE;
constexpr size_t OFF_CLASS  = OFF_POSEQ + (size_t)BPTS * 16;
constexpr size_t OFF_PRED   = OFF_CLASS + (size_t)BPTS;
constexpr size_t OFF_VECQ   = OFF_PRED + (size_t)BPTS * NPOSE;

// workspace: f16 weight fragments (hi/lo), then reverify structures
constexpr size_t WS_W0H = 0;         // f16 element offsets
constexpr size_t WS_W0L = 16384;
constexpr size_t WS_W1H = 32768;
constexpr size_t WS_W1L = 98304;
constexpr size_t WS_W2H = 163840;
constexpr size_t WS_W2L = 229376;
constexpr size_t WB_END   = 589824;              // bytes
constexpr size_t CNT_B    = WB_END;
constexpr size_t PAIRS_B  = WB_END + 1024;
constexpr int    PAIR_CAP = 65536;
constexpr size_t EXACT_B  = PAIRS_B + (size_t)PAIR_CAP * 8;
}

typedef _Float16 f16;
typedef __attribute__((ext_vector_type(4))) _Float16 f16x4;
typedef __attribute__((ext_vector_type(8))) _Float16 f16x8;
typedef __attribute__((ext_vector_type(4))) float    f32x4;

#define MFMA16(a, b, c) __builtin_amdgcn_mfma_f32_16x16x32_f16((a), (b), (c), 0, 0, 0)

// ---- merged weight prep (+ cnt zero): split fp32 W[k][ch] into hi/lo f16 frags.
// idx = ((cht*KC + kc)*64 + lane)*8 + e -> W[k=kc*32+(lane>>4)*8+e][ch=cht*16+(lane&15)]
__global__ __launch_bounds__(256)
void prep_all(const float* __restrict__ w0, const float* __restrict__ w1,
              const float* __restrict__ w2, f16* __restrict__ wf, int* __restrict__ cnt)
{
    const int bid = blockIdx.x, tid = threadIdx.x;
    if (bid == 0 && tid == 0) *cnt = 0;
    if (bid < 64) {                       // w0: KC=2, 16384 frags
        int i = bid * 256 + tid;
        int e  = i & 7;
        int l  = (i >> 3) & 63;
        int kc = (i >> 9) & 1;
        int nt = i >> 10;
        int k   = kc * 32 + ((l >> 4) << 3) + e;
        int col = nt * 16 + (l & 15);
        float v = (k < 39) ? w0[k * HD + col] : 0.f;
        f16 hi = (f16)v;
        wf[WS_W0H + i] = hi;
        wf[WS_W0L + i] = (f16)(v - (float)hi);
    } else {                              // w1/w2: KC=8, 65536 frags each
        const bool is1 = bid < 320;
        const float* w = is1 ? w1 : w2;
        int i = (bid - (is1 ? 64 : 320)) * 256 + tid;
        int e  = i & 7;
        int l  = (i >> 3) & 63;
        int kc = (i >> 9) & 7;
        int nt = i >> 12;
        int k   = kc * 32 + ((l >> 4) << 3) + e;
        int col = nt * 16 + (l & 15);
        float v = w[k * HD + col];
        f16 hi = (f16)v;
        wf[(is1 ? WS_W1H : WS_W2H) + i] = hi;
        wf[(is1 ? WS_W1L : WS_W2L) + i] = (f16)(v - (float)hi);
    }
}

// swizzled byte address in the 512B full-width row: p 0..127, cbyte 0..511
__device__ __forceinline__ int bswz(int p, int cbyte) {
    return p * 512 + (cbyte ^ ((p & 15) << 4));
}

__global__ __launch_bounds__(512, 4)
void mlp_kernel(const float* __restrict__ x_world,
                const float* __restrict__ inv_poses,
                const float* __restrict__ b0, const float* __restrict__ b1,
                const float* __restrict__ b2, const float* __restrict__ w3,
                const float* __restrict__ b3, const f16* __restrict__ wf,
                float* __restrict__ out)
{
    __shared__ char  lds[65536];        // h buffer [128 rows][256 ch f16]; feat overlaps
    __shared__ float predp[TM][8];

    f16* feath = (f16*)lds;             // [128][40] f16 = 10 KB, dead after layer 0

    const int tid  = threadIdx.x;
    const int lane = tid & 63;
    const int wv   = tid >> 6;          // wave id 0..7 = channel group
    const int l15  = lane & 15;
    const int g    = lane >> 4;

    const int bid   = blockIdx.x;
    const int n_idx = bid >> 7;         // 128 blocks per pose
    const int bbase = (bid & 127) * TM;

    // wave wv owns channels cht=wv (cols 0..127 half) and wv+8 (cols 128..255 half)
    // for ALL 128 points: weight fragments read exactly once per block.

    // ---- pose transform + positional encoding (4 threads per point) ----
    {
        const int p   = tid >> 2;       // 0..127
        const int sub = tid & 3;
        const int b   = bbase + p;
        const float xw0 = x_world[b*3+0], xw1 = x_world[b*3+1], xw2 = x_world[b*3+2];
        const float* P = inv_poses + n_idx * 16;
        float xl[3];
        #pragma unroll
        for (int x = 0; x < 3; ++x)
            xl[x] = P[x*4+3] + P[x*4+0]*xw0 + P[x*4+1]*xw1 + P[x*4+2]*xw2;

        auto put = [&](int c, float v) { feath[p*40 + c] = (f16)v; };
        if (sub == 0) {
            float* xla = out + OFF_XLA + ((size_t)n_idx * BPTS + b) * 3;
            #pragma unroll
            for (int x = 0; x < 3; ++x) { xla[x] = xl[x]; put(x, xl[x]); }
            put(39, 0.f);               // k-pad
        }
        #pragma unroll
        for (int t = 0; t < 3; ++t) {   // 12 sin/cos jobs, 3 per sub
            int j = sub * 3 + t;
            int o = j >> 1, fn = j & 1;
            float s = (float)(1 << o);
            #pragma unroll
            for (int x = 0; x < 3; ++x) {
                float a = xl[x] * s;
                put(3 + 6*o + 3*fn + x, fn ? cosf(a) : sinf(a));
            }
        }
    }
    __syncthreads();

    f32x4 acc[2][8];                    // [c2][pt]: 32 channels x 128 points (64 VGPR)

    auto init_bias = [&](const float* bias) {
        #pragma unroll
        for (int c2 = 0; c2 < 2; ++c2) {
            f32x4 bv = *(const f32x4*)(bias + (wv + c2*8) * 16 + g * 4);
            #pragma unroll
            for (int pt = 0; pt < 8; ++pt) acc[c2][pt] = bv;
        }
    };

    // ---- layer 0: feat(39, padded 64) -> acc.  2-term: (wh+wl)*feat_h ----
    init_bias(b0);
    {
        const f16x8 z = {};
        #pragma unroll
        for (int kc = 0; kc < 2; ++kc) {
            #pragma unroll
            for (int half = 0; half < 2; ++half) {
                f16x8 ah[4];
                #pragma unroll
                for (int q = 0; q < 4; ++q) {
                    int p = (half*4 + q) * 16 + l15;
                    if (kc == 0)      ah[q] = *(const f16x8*)&feath[p*40 + g*8];
                    else if (g == 0)  ah[q] = *(const f16x8*)&feath[p*40 + 32];
                    else              ah[q] = z;
                }
                #pragma unroll
                for (int c2 = 0; c2 < 2; ++c2) {
                    int off = (((wv + c2*8) * 2 + kc) * 64 + lane) * 8;
                    f16x8 wh = *(const f16x8*)(wf + WS_W0H + off);
                    f16x8 wl = *(const f16x8*)(wf + WS_W0L + off);
                    #pragma unroll
                    for (int q = 0; q < 4; ++q) {
                        acc[c2][half*4+q] = MFMA16(wh, ah[q], acc[c2][half*4+q]);
                        acc[c2][half*4+q] = MFMA16(wl, ah[q], acc[c2][half*4+q]);
                    }
                }
            }
        }
    }

    auto packone = [&](f32x4 a) {
        return (f16x4){(f16)fmaxf(a[0],0.f), (f16)fmaxf(a[1],0.f),
                       (f16)fmaxf(a[2],0.f), (f16)fmaxf(a[3],0.f)};
    };
    // store 4 consecutive channels (ch = (wv+c2*8)*16 + g*4) for point pt*16+l15
    auto stfrag = [&](int c2, int pt, f16x4 hv) {
        int cbyte = c2 * 256 + wv * 32 + g * 8;
        *(f16x4*)(lds + bswz(pt * 16 + l15, cbyte)) = hv;
    };

    // ---- hidden layer: store all 256 cols, then 8 kcg accumulation steps ----
    auto hd_layer = [&](const float* bias, const f16* wfh, const f16* wfl) {
        __syncthreads();                          // prior buf/feat reads done
        #pragma unroll
        for (int c2 = 0; c2 < 2; ++c2)
            #pragma unroll
            for (int pt = 0; pt < 8; ++pt)
                stfrag(c2, pt, packone(acc[c2][pt]));
        __syncthreads();
        init_bias(bias);
        #pragma unroll
        for (int kcg = 0; kcg < 8; ++kcg) {
            #pragma unroll
            for (int half = 0; half < 2; ++half) {
                f16x8 bh[4];
                #pragma unroll
                for (int q = 0; q < 4; ++q)
                    bh[q] = *(const f16x8*)(lds +
                              bswz((half*4 + q) * 16 + l15, kcg * 64 + g * 16));
                #pragma unroll
                for (int c2 = 0; c2 < 2; ++c2) {
                    int off = (((wv + c2*8) * 8 + kcg) * 64 + lane) * 8;
                    f16x8 wh = *(const f16x8*)(wfh + off);
                    f16x8 wl = *(const f16x8*)(wfl + off);
                    #pragma unroll
                    for (int q = 0; q < 4; ++q) {
                        acc[c2][half*4+q] = MFMA16(wh, bh[q], acc[c2][half*4+q]);
                        acc[c2][half*4+q] = MFMA16(wl, bh[q], acc[c2][half*4+q]);
                    }
                }
            }
        }
    };

    hd_layer(b1, wf + WS_W1H, wf + WS_W1L);
    hd_layer(b2, wf + WS_W2H, wf + WS_W2L);

    // ---- layer 3 from registers: pred[point] = sum_ch relu(h2)*w3[ch] ----
    {
        float pp[8] = {};
        #pragma unroll
        for (int c2 = 0; c2 < 2; ++c2) {
            f32x4 wvv = *(const f32x4*)(w3 + (wv + c2*8) * 16 + g * 4);
            #pragma unroll
            for (int pt = 0; pt < 8; ++pt)
                #pragma unroll
                for (int r = 0; r < 4; ++r)
                    pp[pt] = fmaf(fmaxf(acc[c2][pt][r], 0.f), wvv[r], pp[pt]);
        }
        #pragma unroll
        for (int pt = 0; pt < 8; ++pt) {
            pp[pt] += __shfl_xor(pp[pt], 16);
            pp[pt] += __shfl_xor(pp[pt], 32);
        }
        if (g == 0) {
            #pragma unroll
            for (int pt = 0; pt < 8; ++pt)
                predp[pt * 16 + l15][wv] = pp[pt];
        }
    }
    __syncthreads();
    if (tid < TM) {
        float s = b3[0];
        #pragma unroll
        for (int j = 0; j < 8; ++j) s += predp[tid][j];
        out[OFF_PRED + (size_t)(bbase + tid) * NPOSE + n_idx] = s;
    }
}

// per-point output writer (shared by select & fixup)
__device__ __forceinline__ void write_point(int b, int idx,
                                            const float* __restrict__ x_world,
                                            const float* __restrict__ inv_poses,
                                            const float* __restrict__ vector,
                                            float* __restrict__ out)
{
    float* me = out + OFF_MINENC + (size_t)b * NPOSE;
    #pragma unroll
    for (int n = 0; n < NPOSE; ++n) me[n] = (n == idx) ? 1.f : 0.f;

    const float* P = inv_poses + idx * 16;
    float* pq = out + OFF_POSEQ + (size_t)b * 16;
    #pragma unroll
    for (int m = 0; m < 16; ++m) pq[m] = P[m];

    const float xw0 = x_world[b*3+0], xw1 = x_world[b*3+1], xw2 = x_world[b*3+2];
    float* xl = out + OFF_XLOCAL + (size_t)b * 3;
    #pragma unroll
    for (int x = 0; x < 3; ++x)
        xl[x] = P[x*4+3] + P[x*4+0]*xw0 + P[x*4+1]*xw1 + P[x*4+2]*xw2;

    out[OFF_CLASS + b] = (float)idx;

    const float* vq = vector + idx * KV;
    float* ov = out + OFF_VECQ + (size_t)b * KV;
    #pragma unroll
    for (int m = 0; m < KV; ++m) ov[m] = vq[m];
}

__global__ __launch_bounds__(256)
void select_kernel(const float* __restrict__ x_world,
                   const float* __restrict__ inv_poses,
                   const float* __restrict__ vector,
                   float* __restrict__ out,
                   int* __restrict__ cnt, int2* __restrict__ pairs,
                   float* __restrict__ exact)
{
    const int b = blockIdx.x * 256 + threadIdx.x;
    if (b >= BPTS) return;

    const float* pr = out + OFF_PRED + (size_t)b * NPOSE;
    float best = pr[0], best2 = 3.4e38f;
    int idx = 0;
    #pragma unroll
    for (int n = 1; n < NPOSE; ++n) {
        float v = pr[n];
        if (v < best) { best2 = best; best = v; idx = n; }
        else if (v < best2) { best2 = v; }
    }

    if (best2 - best >= TAU) {
        write_point(b, idx, x_world, inv_poses, vector, out);
    } else {
        #pragma unroll
        for (int n = 0; n < NPOSE; ++n) {
            float v = pr[n];
            if (v < best + TAU) {
                exact[b * NPOSE + n] = v;
                int slot = atomicAdd(cnt, 1);
                if (slot < PAIR_CAP) pairs[slot] = make_int2(b, n);
            }
        }
    }
}

// fp32 exact MLP for flagged pairs: 32 pairs per chunk, 4-row register tiles
template<int KDIM, int RS>
__device__ __forceinline__ void gemm32r4(const float* __restrict__ W,
                                         const float* __restrict__ B,
                                         const float (*in)[RS],
                                         float acc[4][8], int tc, int tr)
{
    {
        float4 bA = *(const float4*)(B + tc*4);
        float4 bB = *(const float4*)(B + 128 + tc*4);
        #pragma unroll
        for (int i = 0; i < 4; ++i) {
            acc[i][0]=bA.x; acc[i][1]=bA.y; acc[i][2]=bA.z; acc[i][3]=bA.w;
            acc[i][4]=bB.x; acc[i][5]=bB.y; acc[i][6]=bB.z; acc[i][7]=bB.w;
        }
    }
    constexpr int K4 = KDIM & ~3;
    #pragma unroll 2
    for (int k = 0; k < K4; k += 4) {
        float4 a4[4];
        #pragma unroll
        for (int i = 0; i < 4; ++i) a4[i] = *(const float4*)&in[tr*4+i][k];
        #pragma unroll
        for (int kk = 0; kk < 4; ++kk) {
            float4 wA = *(const float4*)(W + (size_t)(k+kk)*HD + tc*4);
            float4 wB = *(const float4*)(W + (size_t)(k+kk)*HD + 128 + tc*4);
            #pragma unroll
            for (int i = 0; i < 4; ++i) {
                const float a = (kk==0) ? a4[i].x : (kk==1) ? a4[i].y
                              : (kk==2) ? a4[i].z : a4[i].w;
                acc[i][0] = fmaf(a, wA.x, acc[i][0]);
                acc[i][1] = fmaf(a, wA.y, acc[i][1]);
                acc[i][2] = fmaf(a, wA.z, acc[i][2]);
                acc[i][3] = fmaf(a, wA.w, acc[i][3]);
                acc[i][4] = fmaf(a, wB.x, acc[i][4]);
                acc[i][5] = fmaf(a, wB.y, acc[i][5]);
                acc[i][6] = fmaf(a, wB.z, acc[i][6]);
                acc[i][7] = fmaf(a, wB.w, acc[i][7]);
            }
        }
    }
    if constexpr (K4 < KDIM) {
        #pragma unroll
        for (int k = K4; k < KDIM; ++k) {
            float4 wA = *(const float4*)(W + (size_t)k*HD + tc*4);
            float4 wB = *(const float4*)(W + (size_t)k*HD + 128 + tc*4);
            #pragma unroll
            for (int i = 0; i < 4; ++i) {
                const float a = in[tr*4+i][k];
                acc[i][0] = fmaf(a, wA.x, acc[i][0]);
                acc[i][1] = fmaf(a, wA.y, acc[i][1]);
                acc[i][2] = fmaf(a, wA.z, acc[i][2]);
                acc[i][3] = fmaf(a, wA.w, acc[i][3]);
                acc[i][4] = fmaf(a, wB.x, acc[i][4]);
                acc[i][5] = fmaf(a, wB.y, acc[i][5]);
                acc[i][6] = fmaf(a, wB.z, acc[i][6]);
                acc[i][7] = fmaf(a, wB.w, acc[i][7]);
            }
        }
    }
}

__global__ __launch_bounds__(256, 2)
void recompute_kernel(const float* __restrict__ x_world,
                      const float* __restrict__ inv_poses,
                      const float* __restrict__ w0, const float* __restrict__ b0,
                      const float* __restrict__ w1, const float* __restrict__ b1,
                      const float* __restrict__ w2, const float* __restrict__ b2,
                      const float* __restrict__ w3, const float* __restrict__ b3,
                      const int* __restrict__ cnt, const int2* __restrict__ pairs,
                      float* __restrict__ exact)
{
    __shared__ float feat[32][44];
    __shared__ float h[32][256];
    __shared__ int2  pl[32];

    const int tid = threadIdx.x;
    const int total = min(*cnt, PAIR_CAP);
    const int tc = tid & 31, tr = tid >> 5;

    for (int base = blockIdx.x * 32; base < total; base += gridDim.x * 32) {
        const int nrows = min(32, total - base);
        if (tid < 32) pl[tid] = (tid < nrows) ? pairs[base + tid] : make_int2(0, 0);
        __syncthreads();
        // embed: 8 threads per row
        {
            const int r = tid >> 3, sub = tid & 7;
            const int2 pp = pl[r];
            const int b = pp.x;
            const float xw0 = x_world[b*3+0], xw1 = x_world[b*3+1], xw2 = x_world[b*3+2];
            const float* P = inv_poses + pp.y * 16;
            float xl[3];
            #pragma unroll
            for (int x = 0; x < 3; ++x)
                xl[x] = P[x*4+3] + P[x*4+0]*xw0 + P[x*4+1]*xw1 + P[x*4+2]*xw2;
            if (sub == 0) {
                #pragma unroll
                for (int x = 0; x < 3; ++x) feat[r][x] = xl[x];
            }
            #pragma unroll
            for (int t = 0; t < 2; ++t) {
                int j = sub + 8*t;
                if (j < 12) {
                    int o = j >> 1, fn = j & 1;
                    float s = (float)(1 << o);
                    #pragma unroll
                    for (int x = 0; x < 3; ++x) {
                        float a = xl[x] * s;
                        feat[r][3 + 6*o + 3*fn + x] = fn ? cosf(a) : sinf(a);
                    }
                }
            }
        }
        __syncthreads();

        float acc[4][8];
        gemm32r4<39, 44>(w0, b0, feat, acc, tc, tr);
        #pragma unroll
        for (int i = 0; i < 4; ++i)
            #pragma unroll
            for (int j = 0; j < 8; ++j) {
                int col = (j < 4) ? tc*4 + j : 128 + tc*4 + (j-4);
                h[tr*4+i][col] = fmaxf(acc[i][j], 0.f);
            }
        __syncthreads();
        gemm32r4<HD, HD>(w1, b1, h, acc, tc, tr);
        __syncthreads();
        #pragma unroll
        for (int i = 0; i < 4; ++i)
            #pragma unroll
            for (int j = 0; j < 8; ++j) {
                int col = (j < 4) ? tc*4 + j : 128 + tc*4 + (j-4);
                h[tr*4+i][col] = fmaxf(acc[i][j], 0.f);
            }
        __syncthreads();
        gemm32r4<HD, HD>(w2, b2, h, acc, tc, tr);
        __syncthreads();
        #pragma unroll
        for (int i = 0; i < 4; ++i)
            #pragma unroll
            for (int j = 0; j < 8; ++j) {
                int col = (j < 4) ? tc*4 + j : 128 + tc*4 + (j-4);
                h[tr*4+i][col] = fmaxf(acc[i][j], 0.f);
            }
        __syncthreads();
        if (tid < nrows) {
            float s = b3[0];
            for (int c = 0; c < HD; ++c) s = fmaf(h[tid][c], w3[c], s);
            exact[pl[tid].x * NPOSE + pl[tid].y] = s;
        }
        __syncthreads();
    }
}

__global__ __launch_bounds__(256)
void fixup_kernel(const float* __restrict__ x_world,
                  const float* __restrict__ inv_poses,
                  const float* __restrict__ vector,
                  float* __restrict__ out,
                  const float* __restrict__ exact)
{
    const int b = blockIdx.x * 256 + threadIdx.x;
    if (b >= BPTS) return;

    const float* pr = out + OFF_PRED + (size_t)b * NPOSE;
    float best = pr[0], best2 = 3.4e38f;
    #pragma unroll
    for (int n = 1; n < NPOSE; ++n) {
        float v = pr[n];
        if (v < best) { best2 = best; best = v; }
        else if (v < best2) { best2 = v; }
    }
    if (best2 - best >= TAU) return;

    float ebest = 3.4e38f;
    int idx = 0;
    #pragma unroll
    for (int n = 0; n < NPOSE; ++n) {
        if (pr[n] < best + TAU) {
            float v = exact[b * NPOSE + n];
            if (v < ebest) { ebest = v; idx = n; }
        }
    }
    write_point(b, idx, x_world, inv_poses, vector, out);
}

extern "C" void kernel_launch(void* const* d_in, const int* in_sizes, int n_in,
                              void* d_out, int out_size, void* d_ws, size_t ws_size,
                              hipStream_t stream)
{
    const float* x_world   = (const float*)d_in[0];
    const float* inv_poses = (const float*)d_in[1];
    const float* vector    = (const float*)d_in[2];
    const float* w0 = (const float*)d_in[3];
    const float* b0 = (const float*)d_in[4];
    const float* w1 = (const float*)d_in[5];
    const float* b1 = (const float*)d_in[6];
    const float* w2 = (const float*)d_in[7];
    const float* b2 = (const float*)d_in[8];
    const float* w3 = (const float*)d_in[9];
    const float* b3 = (const float*)d_in[10];
    float* out = (float*)d_out;

    char*  ws    = (char*)d_ws;
    f16*   wf    = (f16*)ws;
    int*   cnt   = (int*)(ws + CNT_B);
    int2*  pairs = (int2*)(ws + PAIRS_B);
    float* exact = (float*)(ws + EXACT_B);

    prep_all<<<dim3(576), dim3(256), 0, stream>>>(w0, w1, w2, wf, cnt);

    mlp_kernel<<<dim3(NPOSE * BPTS / TM), dim3(512), 0, stream>>>(
        x_world, inv_poses, b0, b1, b2, w3, b3, wf, out);
    select_kernel<<<dim3(BPTS / 256), dim3(256), 0, stream>>>(
        x_world, inv_poses, vector, out, cnt, pairs, exact);
    recompute_kernel<<<dim3(1024), dim3(256), 0, stream>>>(
        x_world, inv_poses, w0, b0, w1, b1, w2, b2, w3, b3, cnt, pairs, exact);
    fixup_kernel<<<dim3(BPTS / 256), dim3(256), 0, stream>>>(
        x_world, inv_poses, vector, out, exact);
}

// Round 10
// 411.697 us; speedup vs baseline: 1.1598x; 1.1598x over previous
//
#include <hip/hip_runtime.h>
#include <cmath>

namespace {
constexpr int BPTS  = 16384;
constexpr int NPOSE = 32;
constexpr int KV    = 8;
constexpr int HD    = 256;
constexpr int TM    = 128;      // points per block (mlp)
constexpr float TAU = 0.015f;   // argmin ambiguity threshold (~3x max 2-term err)

constexpr size_t OFF_XLOCAL = 0;
constexpr size_t OFF_XLA    = (size_t)BPTS * 3;
constexpr size_t OFF_MINENC = OFF_XLA + (size_t)NPOSE * BPTS * 3;
constexpr size_t OFF_POSEQ  = OFF_MINENC + (size_t)BPTS * NPOSE;
constexpr size_t OFF_CLASS  = OFF_POSEQ + (size_t)BPTS * 16;
constexpr size_t OFF_PRED   = OFF_CLASS + (size_t)BPTS;
constexpr size_t OFF_VECQ   = OFF_PRED + (size_t)BPTS * NPOSE;

// workspace: f16 weight fragments (hi/lo), then reverify structures
constexpr size_t WS_W0H = 0;         // f16 element offsets
constexpr size_t WS_W0L = 16384;
constexpr size_t WS_W1H = 32768;
constexpr size_t WS_W1L = 98304;
constexpr size_t WS_W2H = 163840;
constexpr size_t WS_W2L = 229376;
constexpr size_t WB_END   = 589824;              // bytes
constexpr size_t CNT_B    = WB_END;
constexpr size_t PAIRS_B  = WB_END + 1024;
constexpr int    PAIR_CAP = 65536;
constexpr size_t EXACT_B  = PAIRS_B + (size_t)PAIR_CAP * 8;
}

typedef _Float16 f16;
typedef __attribute__((ext_vector_type(4))) _Float16 f16x4;
typedef __attribute__((ext_vector_type(8))) _Float16 f16x8;
typedef __attribute__((ext_vector_type(4))) float    f32x4;

#define MFMA16(a, b, c) __builtin_amdgcn_mfma_f32_16x16x32_f16((a), (b), (c), 0, 0, 0)

// ---- merged weight prep (+ cnt zero): split fp32 W[k][ch] into hi/lo f16 frags.
// idx = ((cht*KC + kc)*64 + lane)*8 + e -> W[k=kc*32+(lane>>4)*8+e][ch=cht*16+(lane&15)]
__global__ __launch_bounds__(256)
void prep_all(const float* __restrict__ w0, const float* __restrict__ w1,
              const float* __restrict__ w2, f16* __restrict__ wf, int* __restrict__ cnt)
{
    const int bid = blockIdx.x, tid = threadIdx.x;
    if (bid == 0 && tid == 0) *cnt = 0;
    if (bid < 64) {                       // w0: KC=2, 16384 frags
        int i = bid * 256 + tid;
        int e  = i & 7;
        int l  = (i >> 3) & 63;
        int kc = (i >> 9) & 1;
        int nt = i >> 10;
        int k   = kc * 32 + ((l >> 4) << 3) + e;
        int col = nt * 16 + (l & 15);
        float v = (k < 39) ? w0[k * HD + col] : 0.f;
        f16 hi = (f16)v;
        wf[WS_W0H + i] = hi;
        wf[WS_W0L + i] = (f16)(v - (float)hi);
    } else {                              // w1/w2: KC=8, 65536 frags each
        const bool is1 = bid < 320;
        const float* w = is1 ? w1 : w2;
        int i = (bid - (is1 ? 64 : 320)) * 256 + tid;
        int e  = i & 7;
        int l  = (i >> 3) & 63;
        int kc = (i >> 9) & 7;
        int nt = i >> 12;
        int k   = kc * 32 + ((l >> 4) << 3) + e;
        int col = nt * 16 + (l & 15);
        float v = w[k * HD + col];
        f16 hi = (f16)v;
        wf[(is1 ? WS_W1H : WS_W2H) + i] = hi;
        wf[(is1 ? WS_W1L : WS_W2L) + i] = (f16)(v - (float)hi);
    }
}

// swizzled byte address in the 512B full-width row: p 0..127, cbyte 0..511
__device__ __forceinline__ int bswz(int p, int cbyte) {
    return p * 512 + (cbyte ^ ((p & 15) << 4));
}

// (512,2): empirically unlocks the 128-VGPR cap ((512,4) pins the allocator to 64
// and forced a scratch spill in rounds 5/9). LDS 69.6KB -> 2 blocks/CU either way.
__global__ __launch_bounds__(512, 2)
void mlp_kernel(const float* __restrict__ x_world,
                const float* __restrict__ inv_poses,
                const float* __restrict__ b0, const float* __restrict__ b1,
                const float* __restrict__ b2, const float* __restrict__ w3,
                const float* __restrict__ b3, const f16* __restrict__ wf,
                float* __restrict__ out)
{
    __shared__ char  lds[65536];        // h buffer [128 rows][256 ch f16]; feat overlaps
    __shared__ float predp[TM][8];

    f16* feath = (f16*)lds;             // [128][40] f16 = 10 KB, dead after layer 0

    const int tid  = threadIdx.x;
    const int lane = tid & 63;
    const int wv   = tid >> 6;          // wave id 0..7 = channel group
    const int l15  = lane & 15;
    const int g    = lane >> 4;

    const int bid   = blockIdx.x;
    const int n_idx = bid >> 7;         // 128 blocks per pose
    const int bbase = (bid & 127) * TM;

    // wave wv owns channels cht=wv (cols 0..127 half) and wv+8 (cols 128..255 half)
    // for ALL 128 points: weight fragments read exactly once per block.

    // ---- pose transform + positional encoding (4 threads per point) ----
    {
        const int p   = tid >> 2;       // 0..127
        const int sub = tid & 3;
        const int b   = bbase + p;
        const float xw0 = x_world[b*3+0], xw1 = x_world[b*3+1], xw2 = x_world[b*3+2];
        const float* P = inv_poses + n_idx * 16;
        float xl[3];
        #pragma unroll
        for (int x = 0; x < 3; ++x)
            xl[x] = P[x*4+3] + P[x*4+0]*xw0 + P[x*4+1]*xw1 + P[x*4+2]*xw2;

        auto put = [&](int c, float v) { feath[p*40 + c] = (f16)v; };
        if (sub == 0) {
            float* xla = out + OFF_XLA + ((size_t)n_idx * BPTS + b) * 3;
            #pragma unroll
            for (int x = 0; x < 3; ++x) { xla[x] = xl[x]; put(x, xl[x]); }
            put(39, 0.f);               // k-pad
        }
        #pragma unroll
        for (int t = 0; t < 3; ++t) {   // 12 sin/cos jobs, 3 per sub
            int j = sub * 3 + t;
            int o = j >> 1, fn = j & 1;
            float s = (float)(1 << o);
            #pragma unroll
            for (int x = 0; x < 3; ++x) {
                float a = xl[x] * s;
                put(3 + 6*o + 3*fn + x, fn ? cosf(a) : sinf(a));
            }
        }
    }
    __syncthreads();

    f32x4 acc[2][8];                    // [c2][pt]: 32 channels x 128 points (64 VGPR)

    auto init_bias = [&](const float* bias) {
        #pragma unroll
        for (int c2 = 0; c2 < 2; ++c2) {
            f32x4 bv = *(const f32x4*)(bias + (wv + c2*8) * 16 + g * 4);
            #pragma unroll
            for (int pt = 0; pt < 8; ++pt) acc[c2][pt] = bv;
        }
    };

    // ---- layer 0: feat(39, padded 64) -> acc.  2-term: (wh+wl)*feat_h ----
    init_bias(b0);
    {
        const f16x8 z = {};
        #pragma unroll
        for (int kc = 0; kc < 2; ++kc) {
            #pragma unroll
            for (int half = 0; half < 2; ++half) {
                f16x8 ah[4];
                #pragma unroll
                for (int q = 0; q < 4; ++q) {
                    int p = (half*4 + q) * 16 + l15;
                    if (kc == 0)      ah[q] = *(const f16x8*)&feath[p*40 + g*8];
                    else if (g == 0)  ah[q] = *(const f16x8*)&feath[p*40 + 32];
                    else              ah[q] = z;
                }
                #pragma unroll
                for (int c2 = 0; c2 < 2; ++c2) {
                    int off = (((wv + c2*8) * 2 + kc) * 64 + lane) * 8;
                    f16x8 wh = *(const f16x8*)(wf + WS_W0H + off);
                    f16x8 wl = *(const f16x8*)(wf + WS_W0L + off);
                    #pragma unroll
                    for (int q = 0; q < 4; ++q) {
                        acc[c2][half*4+q] = MFMA16(wh, ah[q], acc[c2][half*4+q]);
                        acc[c2][half*4+q] = MFMA16(wl, ah[q], acc[c2][half*4+q]);
                    }
                }
            }
        }
    }

    auto packone = [&](f32x4 a) {
        return (f16x4){(f16)fmaxf(a[0],0.f), (f16)fmaxf(a[1],0.f),
                       (f16)fmaxf(a[2],0.f), (f16)fmaxf(a[3],0.f)};
    };
    // store 4 consecutive channels (ch = (wv+c2*8)*16 + g*4) for point pt*16+l15
    auto stfrag = [&](int c2, int pt, f16x4 hv) {
        int cbyte = c2 * 256 + wv * 32 + g * 8;
        *(f16x4*)(lds + bswz(pt * 16 + l15, cbyte)) = hv;
    };

    // ---- hidden layer: store all 256 cols, then 8 kcg accumulation steps ----
    auto hd_layer = [&](const float* bias, const f16* wfh, const f16* wfl) {
        __syncthreads();                          // prior buf/feat reads done
        #pragma unroll
        for (int c2 = 0; c2 < 2; ++c2)
            #pragma unroll
            for (int pt = 0; pt < 8; ++pt)
                stfrag(c2, pt, packone(acc[c2][pt]));
        __syncthreads();
        init_bias(bias);
        #pragma unroll
        for (int kcg = 0; kcg < 8; ++kcg) {
            #pragma unroll
            for (int half = 0; half < 2; ++half) {
                f16x8 bh[4];
                #pragma unroll
                for (int q = 0; q < 4; ++q)
                    bh[q] = *(const f16x8*)(lds +
                              bswz((half*4 + q) * 16 + l15, kcg * 64 + g * 16));
                #pragma unroll
                for (int c2 = 0; c2 < 2; ++c2) {
                    int off = (((wv + c2*8) * 8 + kcg) * 64 + lane) * 8;
                    f16x8 wh = *(const f16x8*)(wfh + off);
                    f16x8 wl = *(const f16x8*)(wfl + off);
                    #pragma unroll
                    for (int q = 0; q < 4; ++q) {
                        acc[c2][half*4+q] = MFMA16(wh, bh[q], acc[c2][half*4+q]);
                        acc[c2][half*4+q] = MFMA16(wl, bh[q], acc[c2][half*4+q]);
                    }
                }
            }
        }
    };

    hd_layer(b1, wf + WS_W1H, wf + WS_W1L);
    hd_layer(b2, wf + WS_W2H, wf + WS_W2L);

    // ---- layer 3 from registers: pred[point] = sum_ch relu(h2)*w3[ch] ----
    {
        float pp[8] = {};
        #pragma unroll
        for (int c2 = 0; c2 < 2; ++c2) {
            f32x4 wvv = *(const f32x4*)(w3 + (wv + c2*8) * 16 + g * 4);
            #pragma unroll
            for (int pt = 0; pt < 8; ++pt)
                #pragma unroll
                for (int r = 0; r < 4; ++r)
                    pp[pt] = fmaf(fmaxf(acc[c2][pt][r], 0.f), wvv[r], pp[pt]);
        }
        #pragma unroll
        for (int pt = 0; pt < 8; ++pt) {
            pp[pt] += __shfl_xor(pp[pt], 16);
            pp[pt] += __shfl_xor(pp[pt], 32);
        }
        if (g == 0) {
            #pragma unroll
            for (int pt = 0; pt < 8; ++pt)
                predp[pt * 16 + l15][wv] = pp[pt];
        }
    }
    __syncthreads();
    if (tid < TM) {
        float s = b3[0];
        #pragma unroll
        for (int j = 0; j < 8; ++j) s += predp[tid][j];
        out[OFF_PRED + (size_t)(bbase + tid) * NPOSE + n_idx] = s;
    }
}

// per-point output writer (shared by select & fixup)
__device__ __forceinline__ void write_point(int b, int idx,
                                            const float* __restrict__ x_world,
                                            const float* __restrict__ inv_poses,
                                            const float* __restrict__ vector,
                                            float* __restrict__ out)
{
    float* me = out + OFF_MINENC + (size_t)b * NPOSE;
    #pragma unroll
    for (int n = 0; n < NPOSE; ++n) me[n] = (n == idx) ? 1.f : 0.f;

    const float* P = inv_poses + idx * 16;
    float* pq = out + OFF_POSEQ + (size_t)b * 16;
    #pragma unroll
    for (int m = 0; m < 16; ++m) pq[m] = P[m];

    const float xw0 = x_world[b*3+0], xw1 = x_world[b*3+1], xw2 = x_world[b*3+2];
    float* xl = out + OFF_XLOCAL + (size_t)b * 3;
    #pragma unroll
    for (int x = 0; x < 3; ++x)
        xl[x] = P[x*4+3] + P[x*4+0]*xw0 + P[x*4+1]*xw1 + P[x*4+2]*xw2;

    out[OFF_CLASS + b] = (float)idx;

    const float* vq = vector + idx * KV;
    float* ov = out + OFF_VECQ + (size_t)b * KV;
    #pragma unroll
    for (int m = 0; m < KV; ++m) ov[m] = vq[m];
}

__global__ __launch_bounds__(256)
void select_kernel(const float* __restrict__ x_world,
                   const float* __restrict__ inv_poses,
                   const float* __restrict__ vector,
                   float* __restrict__ out,
                   int* __restrict__ cnt, int2* __restrict__ pairs,
                   float* __restrict__ exact)
{
    const int b = blockIdx.x * 256 + threadIdx.x;
    if (b >= BPTS) return;

    const float* pr = out + OFF_PRED + (size_t)b * NPOSE;
    float best = pr[0], best2 = 3.4e38f;
    int idx = 0;
    #pragma unroll
    for (int n = 1; n < NPOSE; ++n) {
        float v = pr[n];
        if (v < best) { best2 = best; best = v; idx = n; }
        else if (v < best2) { best2 = v; }
    }

    if (best2 - best >= TAU) {
        write_point(b, idx, x_world, inv_poses, vector, out);
    } else {
        #pragma unroll
        for (int n = 0; n < NPOSE; ++n) {
            float v = pr[n];
            if (v < best + TAU) {
                exact[b * NPOSE + n] = v;
                int slot = atomicAdd(cnt, 1);
                if (slot < PAIR_CAP) pairs[slot] = make_int2(b, n);
            }
        }
    }
}

// fp32 exact MLP for flagged pairs: 32 pairs/chunk, 512 threads, 2-row tiles
template<int KDIM, int RS>
__device__ __forceinline__ void gemm32r2(const float* __restrict__ W,
                                         const float* __restrict__ B,
                                         const float (*in)[RS],
                                         float acc[2][8], int tc, int tr)
{
    {
        float4 bA = *(const float4*)(B + tc*4);
        float4 bB = *(const float4*)(B + 128 + tc*4);
        #pragma unroll
        for (int i = 0; i < 2; ++i) {
            acc[i][0]=bA.x; acc[i][1]=bA.y; acc[i][2]=bA.z; acc[i][3]=bA.w;
            acc[i][4]=bB.x; acc[i][5]=bB.y; acc[i][6]=bB.z; acc[i][7]=bB.w;
        }
    }
    constexpr int K4 = KDIM & ~3;
    #pragma unroll 2
    for (int k = 0; k < K4; k += 4) {
        float4 a4[2];
        #pragma unroll
        for (int i = 0; i < 2; ++i) a4[i] = *(const float4*)&in[tr*2+i][k];
        #pragma unroll
        for (int kk = 0; kk < 4; ++kk) {
            float4 wA = *(const float4*)(W + (size_t)(k+kk)*HD + tc*4);
            float4 wB = *(const float4*)(W + (size_t)(k+kk)*HD + 128 + tc*4);
            #pragma unroll
            for (int i = 0; i < 2; ++i) {
                const float a = (kk==0) ? a4[i].x : (kk==1) ? a4[i].y
                              : (kk==2) ? a4[i].z : a4[i].w;
                acc[i][0] = fmaf(a, wA.x, acc[i][0]);
                acc[i][1] = fmaf(a, wA.y, acc[i][1]);
                acc[i][2] = fmaf(a, wA.z, acc[i][2]);
                acc[i][3] = fmaf(a, wA.w, acc[i][3]);
                acc[i][4] = fmaf(a, wB.x, acc[i][4]);
                acc[i][5] = fmaf(a, wB.y, acc[i][5]);
                acc[i][6] = fmaf(a, wB.z, acc[i][6]);
                acc[i][7] = fmaf(a, wB.w, acc[i][7]);
            }
        }
    }
    if constexpr (K4 < KDIM) {
        #pragma unroll
        for (int k = K4; k < KDIM; ++k) {
            float4 wA = *(const float4*)(W + (size_t)k*HD + tc*4);
            float4 wB = *(const float4*)(W + (size_t)k*HD + 128 + tc*4);
            #pragma unroll
            for (int i = 0; i < 2; ++i) {
                const float a = in[tr*2+i][k];
                acc[i][0] = fmaf(a, wA.x, acc[i][0]);
                acc[i][1] = fmaf(a, wA.y, acc[i][1]);
                acc[i][2] = fmaf(a, wA.z, acc[i][2]);
                acc[i][3] = fmaf(a, wA.w, acc[i][3]);
                acc[i][4] = fmaf(a, wB.x, acc[i][4]);
                acc[i][5] = fmaf(a, wB.y, acc[i][5]);
                acc[i][6] = fmaf(a, wB.z, acc[i][6]);
                acc[i][7] = fmaf(a, wB.w, acc[i][7]);
            }
        }
    }
}

__global__ __launch_bounds__(512, 2)
void recompute_kernel(const float* __restrict__ x_world,
                      const float* __restrict__ inv_poses,
                      const float* __restrict__ w0, const float* __restrict__ b0,
                      const float* __restrict__ w1, const float* __restrict__ b1,
                      const float* __restrict__ w2, const float* __restrict__ b2,
                      const float* __restrict__ w3, const float* __restrict__ b3,
                      const int* __restrict__ cnt, const int2* __restrict__ pairs,
                      float* __restrict__ exact)
{
    __shared__ float feat[32][44];
    __shared__ float h[32][256];
    __shared__ int2  pl[32];

    const int tid = threadIdx.x;
    const int total = min(*cnt, PAIR_CAP);
    const int tc = tid & 31, tr = tid >> 5;     // 16 row-groups x 2 rows

    for (int base = blockIdx.x * 32; base < total; base += gridDim.x * 32) {
        const int nrows = min(32, total - base);
        if (tid < 32) pl[tid] = (tid < nrows) ? pairs[base + tid] : make_int2(0, 0);
        __syncthreads();
        // embed: 16 threads per row
        {
            const int r = tid >> 4, sub = tid & 15;
            const int2 pp = pl[r];
            const int b = pp.x;
            const float xw0 = x_world[b*3+0], xw1 = x_world[b*3+1], xw2 = x_world[b*3+2];
            const float* P = inv_poses + pp.y * 16;
            float xl[3];
            #pragma unroll
            for (int x = 0; x < 3; ++x)
                xl[x] = P[x*4+3] + P[x*4+0]*xw0 + P[x*4+1]*xw1 + P[x*4+2]*xw2;
            if (sub == 12) {
                #pragma unroll
                for (int x = 0; x < 3; ++x) feat[r][x] = xl[x];
            }
            if (sub < 12) {
                int o = sub >> 1, fn = sub & 1;
                float s = (float)(1 << o);
                #pragma unroll
                for (int x = 0; x < 3; ++x) {
                    float a = xl[x] * s;
                    feat[r][3 + 6*o + 3*fn + x] = fn ? cosf(a) : sinf(a);
                }
            }
        }
        __syncthreads();

        float acc[2][8];
        gemm32r2<39, 44>(w0, b0, feat, acc, tc, tr);
        #pragma unroll
        for (int i = 0; i < 2; ++i)
            #pragma unroll
            for (int j = 0; j < 8; ++j) {
                int col = (j < 4) ? tc*4 + j : 128 + tc*4 + (j-4);
                h[tr*2+i][col] = fmaxf(acc[i][j], 0.f);
            }
        __syncthreads();
        gemm32r2<HD, HD>(w1, b1, h, acc, tc, tr);
        __syncthreads();
        #pragma unroll
        for (int i = 0; i < 2; ++i)
            #pragma unroll
            for (int j = 0; j < 8; ++j) {
                int col = (j < 4) ? tc*4 + j : 128 + tc*4 + (j-4);
                h[tr*2+i][col] = fmaxf(acc[i][j], 0.f);
            }
        __syncthreads();
        gemm32r2<HD, HD>(w2, b2, h, acc, tc, tr);
        __syncthreads();
        #pragma unroll
        for (int i = 0; i < 2; ++i)
            #pragma unroll
            for (int j = 0; j < 8; ++j) {
                int col = (j < 4) ? tc*4 + j : 128 + tc*4 + (j-4);
                h[tr*2+i][col] = fmaxf(acc[i][j], 0.f);
            }
        __syncthreads();
        if (tid < nrows) {
            float s = b3[0];
            for (int c = 0; c < HD; ++c) s = fmaf(h[tid][c], w3[c], s);
            exact[pl[tid].x * NPOSE + pl[tid].y] = s;
        }
        __syncthreads();
    }
}

__global__ __launch_bounds__(256)
void fixup_kernel(const float* __restrict__ x_world,
                  const float* __restrict__ inv_poses,
                  const float* __restrict__ vector,
                  float* __restrict__ out,
                  const float* __restrict__ exact)
{
    const int b = blockIdx.x * 256 + threadIdx.x;
    if (b >= BPTS) return;

    const float* pr = out + OFF_PRED + (size_t)b * NPOSE;
    float best = pr[0], best2 = 3.4e38f;
    #pragma unroll
    for (int n = 1; n < NPOSE; ++n) {
        float v = pr[n];
        if (v < best) { best2 = best; best = v; }
        else if (v < best2) { best2 = v; }
    }
    if (best2 - best >= TAU) return;

    float ebest = 3.4e38f;
    int idx = 0;
    #pragma unroll
    for (int n = 0; n < NPOSE; ++n) {
        if (pr[n] < best + TAU) {
            float v = exact[b * NPOSE + n];
            if (v < ebest) { ebest = v; idx = n; }
        }
    }
    write_point(b, idx, x_world, inv_poses, vector, out);
}

extern "C" void kernel_launch(void* const* d_in, const int* in_sizes, int n_in,
                              void* d_out, int out_size, void* d_ws, size_t ws_size,
                              hipStream_t stream)
{
    const float* x_world   = (const float*)d_in[0];
    const float* inv_poses = (const float*)d_in[1];
    const float* vector    = (const float*)d_in[2];
    const float* w0 = (const float*)d_in[3];
    const float* b0 = (const float*)d_in[4];
    const float* w1 = (const float*)d_in[5];
    const float* b1 = (const float*)d_in[6];
    const float* w2 = (const float*)d_in[7];
    const float* b2 = (const float*)d_in[8];
    const float* w3 = (const float*)d_in[9];
    const float* b3 = (const float*)d_in[10];
    float* out = (float*)d_out;

    char*  ws    = (char*)d_ws;
    f16*   wf    = (f16*)ws;
    int*   cnt   = (int*)(ws + CNT_B);
    int2*  pairs = (int2*)(ws + PAIRS_B);
    float* exact = (float*)(ws + EXACT_B);

    prep_all<<<dim3(576), dim3(256), 0, stream>>>(w0, w1, w2, wf, cnt);

    mlp_kernel<<<dim3(NPOSE * BPTS / TM), dim3(512), 0, stream>>>(
        x_world, inv_poses, b0, b1, b2, w3, b3, wf, out);
    select_kernel<<<dim3(BPTS / 256), dim3(256), 0, stream>>>(
        x_world, inv_poses, vector, out, cnt, pairs, exact);
    recompute_kernel<<<dim3(512), dim3(512), 0, stream>>>(
        x_world, inv_poses, w0, b0, w1, b1, w2, b2, w3, b3, cnt, pairs, exact);
    fixup_kernel<<<dim3(BPTS / 256), dim3(256), 0, stream>>>(
        x_world, inv_poses, vector, out, exact);
}